// Round 4
// baseline (108.949 us; speedup 1.0000x reference)
//
#include <hip/hip_runtime.h>
#include <math.h>

// Problem constants
#define B_ 8
#define T_ 256
#define A_ 2
#define C_ 128
#define R_ 128
#define H_ 128
#define OUT_ 256

// Workspace layout (float offsets) -- only the prep projections now.
#define WS_PCK 0
#define WS_PCV 16384
#define WS_PSK 32768
#define WS_PSV 33792
#define WS_QK  34816
#define WS_TOTAL 34944   // floats (~137 KB)

// Offsets (floats) inside main_kernel's 64KB multi-use LDS region U[16384]:
//   [0     .. 4096)  W1 plane chunk  [32 c][128 r]
//   [4096  .. 8192)  W2 plane chunk
//   [8192  ..12288)  W3 plane chunk
//   [12288 ..12416)  wL   : softmax weights w[c]
//   [12416 ..12928)  part : score partials [128 c][4 rs]
// Later the whole region is reused as the transpose buffer float4[4][8][128]
// and then as the epilogue buffer float4[4][16][64].
#define WL_OFF   12288
#define PART_OFF 12416

// gelu via A&S 7.1.27 (|erf err| <= 5e-4), no exp, branchless (scores path).
__device__ __forceinline__ float gelu_fast(float x) {
    const float ax = fabsf(x);
    float q = fmaf(ax, 0.019527f, 0.000343654f);
    q = fmaf(q, ax, 0.1151945f);
    q = fmaf(q, ax, 0.19685217f);
    q = fmaf(q, ax, 1.0f);
    const float r  = __builtin_amdgcn_rcpf(q);
    const float r2 = r * r;
    const float r4 = r2 * r2;
    return fmaf(-0.5f * ax, r4, fmaxf(x, 0.0f));
}

// ---------------------------------------------------------------------------
// Kernel 1: small projection dots into workspace.
// ---------------------------------------------------------------------------
__global__ __launch_bounds__(256) void prep_kernel(
    const float* __restrict__ session,   // [B,H]
    const float* __restrict__ query,     // [R]
    const float* __restrict__ pos,       // [C,R]
    const float* __restrict__ kW1,       // [R+H, R]
    const float* __restrict__ kb1,       // [R]
    const float* __restrict__ kW2,       // [R, R]
    const float* __restrict__ vW1,       // [R+H+1, R]
    const float* __restrict__ vb1,       // [R]
    float* __restrict__ ws)
{
    const int g = blockIdx.x * 256 + threadIdx.x;
    if (g < 16384) {                       // pck[c][r]
        const int c = g >> 7, r = g & 127;
        float acc = 0.0f;
        #pragma unroll 16
        for (int k = 0; k < R_; ++k)
            acc += pos[c * R_ + k] * kW1[k * R_ + r];
        ws[WS_PCK + g] = acc;
    } else if (g < 32768) {                // pcv[c][r]
        const int e = g - 16384;
        const int c = e >> 7, r = e & 127;
        float acc = 0.0f;
        #pragma unroll 16
        for (int k = 0; k < R_; ++k)
            acc += pos[c * R_ + k] * vW1[k * R_ + r];
        ws[WS_PCV + e] = acc;
    } else if (g < 33792) {                // psk[b][r] (+kb1)
        const int e = g - 32768;
        const int b = e >> 7, r = e & 127;
        float acc = kb1[r];
        #pragma unroll 16
        for (int k = 0; k < H_; ++k)
            acc += session[b * H_ + k] * kW1[(R_ + k) * R_ + r];
        ws[WS_PSK + e] = acc;
    } else if (g < 34816) {                // psv[b][r] (+vb1)
        const int e = g - 33792;
        const int b = e >> 7, r = e & 127;
        float acc = vb1[r];
        #pragma unroll 16
        for (int k = 0; k < H_; ++k)
            acc += session[b * H_ + k] * vW1[(R_ + k) * R_ + r];
        ws[WS_PSV + e] = acc;
    } else if (g < 34944) {                // qk[r] = kW2[r,:] . query
        const int r = g - 34816;
        float acc = 0.0f;
        #pragma unroll 16
        for (int j = 0; j < R_; ++j)
            acc += kW2[r * R_ + j] * query[j];
        ws[WS_QK + r] = acc;
    }
}

// ---------------------------------------------------------------------------
// Kernel 2 (FUSED): scores + softmax + coefficient planes + Taylor GEMM +
// epilogue. 256 blocks x 512 threads; 16 (t,a) rows per block, 1 block/CU.
// Softmax/coef are recomputed per block (cheap: ~0.4 + ~2 us crit-path)
// in exchange for killing two kernel launches, the 8-CU serial softmax
// kernel, and the 50 MB L2 plane round-trip (planes now live in LDS).
// LDS = 8K(sv) + 64K(U multi-use) + 8K(p4) = 80 KB exactly (2-block capacity).
// (Resubmission of R3 -- bench infra failed; kernel re-audited, no changes.)
// ---------------------------------------------------------------------------
__global__ __launch_bounds__(512) void main_kernel(
    const float* __restrict__ state,  // [B, 512, 128] rows
    const float* __restrict__ vW1,    // [R+H+1, R]; last row = vr
    const float* __restrict__ vW2,    // [R, OUT]
    const float* __restrict__ vb2,    // [OUT]
    const float* __restrict__ ws,
    float* __restrict__ out)          // [B, 512, OUT]
{
    __shared__ __align__(16) float sv[16 * C_];   // 16 state rows (8 KB);
                                                  // reused for S0 partials
    __shared__ __align__(16) float U[16384];      // 64 KB multi-use (see top)
    __shared__ float4 p4[4][R_];                  // combined partials, 8 KB

    const int blk = blockIdx.x;
    const int b   = blk >> 5;        // / 32
    const int grp = blk & 31;
    const int tid = threadIdx.x;

    // ---- load 16 state rows ----
    const float* __restrict__ srow = state + (size_t)(b * 512 + grp * 16) * C_;
    #pragma unroll
    for (int i = 0; i < 4; ++i) sv[tid + 512 * i] = srow[tid + 512 * i];

    // ---- scores: part[c][rs], thread = (c = tid>>2, rs = tid&3) ----
    {
        const int c  = tid >> 2;
        const int rs = tid & 3;
        const float4* __restrict__ pk4 = (const float4*)(ws + WS_PCK + c * R_ + rs * 32);
        const float4* __restrict__ ps4 = (const float4*)(ws + WS_PSK + b * R_ + rs * 32);
        const float4* __restrict__ qk4 = (const float4*)(ws + WS_QK + rs * 32);
        float acc = 0.0f;
        #pragma unroll
        for (int i = 0; i < 8; ++i) {
            const float4 pk = pk4[i];
            const float4 ps = ps4[i];
            const float4 qq = qk4[i];
            acc += gelu_fast(pk.x + ps.x) * qq.x;
            acc += gelu_fast(pk.y + ps.y) * qq.y;
            acc += gelu_fast(pk.z + ps.z) * qq.z;
            acc += gelu_fast(pk.w + ps.w) * qq.w;
        }
        U[PART_OFF + c * 4 + rs] = acc;
    }
    __syncthreads();

    // ---- softmax on wave 0 (2 c's per lane, shuffle reductions) ----
    if (tid < 64) {
        const float4 pa = *(const float4*)&U[PART_OFF + tid * 8];
        const float4 pb = *(const float4*)&U[PART_OFF + tid * 8 + 4];
        float s0 = (pa.x + pa.y + pa.z + pa.w) * 0.08838834764831845f;
        float s1 = (pb.x + pb.y + pb.z + pb.w) * 0.08838834764831845f;
        float m = fmaxf(s0, s1);
        #pragma unroll
        for (int off = 32; off > 0; off >>= 1) m = fmaxf(m, __shfl_xor(m, off));
        const float e0 = __expf(s0 - m);
        const float e1 = __expf(s1 - m);
        float sum = e0 + e1;
        #pragma unroll
        for (int off = 32; off > 0; off >>= 1) sum += __shfl_xor(sum, off);
        U[WL_OFF + tid * 2 + 0] = e0 / sum;
        U[WL_OFF + tid * 2 + 1] = e1 / sum;
    }
    __syncthreads();

    // ---- chunk loop: coef planes into LDS, then phase-2 partial ----
    // coef mapping: thread = (cg = tid>>7 handling 8 c's, rcoef = tid&127)
    const int rcoef = tid & 127;
    const int cg    = tid >> 7;
    const float vr   = vW1[(R_ + H_) * R_ + rcoef];
    const float vr2  = vr * vr;
    const float vr3  = vr2 * vr;
    const float psvr = ws[WS_PSV + b * R_ + rcoef];

    // phase-2 mapping: thread = (rh = tid>>8, seg = (tid&255)>>5, k = tid&31)
    const int rh    = tid >> 8;
    const int t2    = tid & 255;
    const int k     = t2 & 31;
    const int seg   = t2 >> 5;
    const int r0    = k * 4;
    const int rbase = rh * 8;

    float4 a[8];
    #pragma unroll
    for (int j = 0; j < 8; ++j) a[j] = make_float4(0.f, 0.f, 0.f, 0.f);
    float s0reg = 0.0f;

    for (int chunk = 0; chunk < 4; ++chunk) {
        // coef-compute: 8 c per thread, write planes W1/W2/W3 [cl][r]
        #pragma unroll
        for (int j = 0; j < 8; ++j) {
            const int cl = cg * 8 + j;
            const int c  = chunk * 32 + cl;
            const float cc  = ws[WS_PCV + c * R_ + rcoef] + psvr;
            const float wgt = U[WL_OFF + c];
            // Phi(cc) via A&S 7.1.27 on |cc| (coeffs pre-folded with 1/sqrt2)
            const float ax = fabsf(cc);
            float qq = fmaf(ax, 0.019527f, 0.000343654f);
            qq = fmaf(qq, ax, 0.1151945f);
            qq = fmaf(qq, ax, 0.19685217f);
            qq = fmaf(qq, ax, 1.0f);
            const float qi  = __builtin_amdgcn_rcpf(qq);
            const float qi2 = qi * qi;
            const float hh  = 0.5f * qi2 * qi2;          // = Phi(-|cc|)
            const float Phi = (cc >= 0.0f) ? (1.0f - hh) : hh;
            const float cc2 = cc * cc;
            const float phi = 0.3989422804f * __expf(-0.5f * cc2);
            const float g0 = cc * Phi;
            const float g1 = fmaf(cc, phi, Phi);
            const float g2 = 0.5f * phi * (2.0f - cc2);
            const float g3 = phi * cc * (cc2 - 4.0f) * (1.0f / 6.0f);
            U[       cl * R_ + rcoef] = wgt * g1 * vr;
            U[4096 + cl * R_ + rcoef] = wgt * g2 * vr2;
            U[8192 + cl * R_ + rcoef] = wgt * g3 * vr3;
            s0reg += wgt * g0;
        }
        __syncthreads();

        // phase-2 partial over this chunk's 32 c (4 c per seg)
        #pragma unroll
        for (int i = 0; i < 4; ++i) {
            const int cl = seg * 4 + i;
            const int c  = chunk * 32 + cl;
            const float4 w1 = *(const float4*)&U[       cl * R_ + r0];
            const float4 w2 = *(const float4*)&U[4096 + cl * R_ + r0];
            const float4 w3 = *(const float4*)&U[8192 + cl * R_ + r0];
            #pragma unroll
            for (int j = 0; j < 8; ++j) {
                const float s  = sv[(rbase + j) * C_ + c];
                const float s2 = s * s;
                const float s3 = s2 * s;
                a[j].x = fmaf(w1.x, s, a[j].x); a[j].x = fmaf(w2.x, s2, a[j].x); a[j].x = fmaf(w3.x, s3, a[j].x);
                a[j].y = fmaf(w1.y, s, a[j].y); a[j].y = fmaf(w2.y, s2, a[j].y); a[j].y = fmaf(w3.y, s3, a[j].y);
                a[j].z = fmaf(w1.z, s, a[j].z); a[j].z = fmaf(w2.z, s2, a[j].z); a[j].z = fmaf(w3.z, s3, a[j].z);
                a[j].w = fmaf(w1.w, s, a[j].w); a[j].w = fmaf(w2.w, s2, a[j].w); a[j].w = fmaf(w3.w, s3, a[j].w);
            }
        }
        __syncthreads();   // protects plane overwrite next chunk / transpose
    }

    // ---- transpose partials into U (planes dead); S0 partials into sv ----
    float4 (*tp)[8][R_] = (float4 (*)[8][R_])U;   // [rquad][seg][r]
    tp[rh * 2 + 0][seg][r0 + 0] = make_float4(a[0].x, a[1].x, a[2].x, a[3].x);
    tp[rh * 2 + 0][seg][r0 + 1] = make_float4(a[0].y, a[1].y, a[2].y, a[3].y);
    tp[rh * 2 + 0][seg][r0 + 2] = make_float4(a[0].z, a[1].z, a[2].z, a[3].z);
    tp[rh * 2 + 0][seg][r0 + 3] = make_float4(a[0].w, a[1].w, a[2].w, a[3].w);
    tp[rh * 2 + 1][seg][r0 + 0] = make_float4(a[4].x, a[5].x, a[6].x, a[7].x);
    tp[rh * 2 + 1][seg][r0 + 1] = make_float4(a[4].y, a[5].y, a[6].y, a[7].y);
    tp[rh * 2 + 1][seg][r0 + 2] = make_float4(a[4].z, a[5].z, a[6].z, a[7].z);
    tp[rh * 2 + 1][seg][r0 + 3] = make_float4(a[4].w, a[5].w, a[6].w, a[7].w);
    sv[cg * R_ + rcoef] = s0reg;                  // state rows dead here
    __syncthreads();

    // ---- seg-reduction: all 512 threads. qd = row-quad, rr = r ----
    {
        const int qd = tid >> 7;         // 0..3
        const int rr = tid & 127;
        float4 v = tp[qd][0][rr];
        #pragma unroll
        for (int sg = 1; sg < 8; ++sg) {
            const float4 t = tp[qd][sg][rr];
            v.x += t.x; v.y += t.y; v.z += t.z; v.w += t.w;
        }
        const float s0v = sv[rr] + sv[R_ + rr] + sv[2 * R_ + rr] + sv[3 * R_ + rr];
        v.x += s0v; v.y += s0v; v.z += s0v; v.w += s0v;
        p4[qd][rr] = v;
    }
    __syncthreads();   // tp dead; U reused as ep[4][16][64]

    // ---- epilogue: split-K register-tiled GEMM; (erh, kq, hq) ----
    float4 (*ep)[16][64] = (float4 (*)[16][64])U;   // [kq][row][hq], 64 KB
    const int hq  = tid & 63;
    const int kq  = (tid >> 6) & 3;
    const int erh = tid >> 8;
    const int h0  = hq * 4;

    float4 o[8];
    #pragma unroll
    for (int j = 0; j < 8; ++j) o[j] = make_float4(0.f, 0.f, 0.f, 0.f);
    const int rrb = kq * 32;
    #pragma unroll 4
    for (int i = 0; i < 32; ++i) {
        const int rr = rrb + i;
        const float4 plo = p4[erh * 2 + 0][rr];                    // broadcast
        const float4 phi = p4[erh * 2 + 1][rr];                    // broadcast
        const float4 wv4 = *(const float4*)(vW2 + rr * OUT_ + h0); // coalesced
        o[0].x = fmaf(plo.x, wv4.x, o[0].x); o[0].y = fmaf(plo.x, wv4.y, o[0].y);
        o[0].z = fmaf(plo.x, wv4.z, o[0].z); o[0].w = fmaf(plo.x, wv4.w, o[0].w);
        o[1].x = fmaf(plo.y, wv4.x, o[1].x); o[1].y = fmaf(plo.y, wv4.y, o[1].y);
        o[1].z = fmaf(plo.y, wv4.z, o[1].z); o[1].w = fmaf(plo.y, wv4.w, o[1].w);
        o[2].x = fmaf(plo.z, wv4.x, o[2].x); o[2].y = fmaf(plo.z, wv4.y, o[2].y);
        o[2].z = fmaf(plo.z, wv4.z, o[2].z); o[2].w = fmaf(plo.z, wv4.w, o[2].w);
        o[3].x = fmaf(plo.w, wv4.x, o[3].x); o[3].y = fmaf(plo.w, wv4.y, o[3].y);
        o[3].z = fmaf(plo.w, wv4.z, o[3].z); o[3].w = fmaf(plo.w, wv4.w, o[3].w);
        o[4].x = fmaf(phi.x, wv4.x, o[4].x); o[4].y = fmaf(phi.x, wv4.y, o[4].y);
        o[4].z = fmaf(phi.x, wv4.z, o[4].z); o[4].w = fmaf(phi.x, wv4.w, o[4].w);
        o[5].x = fmaf(phi.y, wv4.x, o[5].x); o[5].y = fmaf(phi.y, wv4.y, o[5].y);
        o[5].z = fmaf(phi.y, wv4.z, o[5].z); o[5].w = fmaf(phi.y, wv4.w, o[5].w);
        o[6].x = fmaf(phi.z, wv4.x, o[6].x); o[6].y = fmaf(phi.z, wv4.y, o[6].y);
        o[6].z = fmaf(phi.z, wv4.z, o[6].z); o[6].w = fmaf(phi.z, wv4.w, o[6].w);
        o[7].x = fmaf(phi.w, wv4.x, o[7].x); o[7].y = fmaf(phi.w, wv4.y, o[7].y);
        o[7].z = fmaf(phi.w, wv4.z, o[7].z); o[7].w = fmaf(phi.w, wv4.w, o[7].w);
    }
    #pragma unroll
    for (int j = 0; j < 8; ++j) ep[kq][erh * 8 + j][hq] = o[j];
    __syncthreads();

    // ---- final combine: thread = (row = tid>>5 (0..15), hq2 = tid&31) ----
    const int row  = tid >> 5;
    const int hqa  = tid & 31;
    float* __restrict__ orow = out + (size_t)(b * 512 + grp * 16 + row) * OUT_;
    #pragma unroll
    for (int half = 0; half < 2; ++half) {
        const int hh = hqa + half * 32;
        const float4 e0 = ep[0][row][hh];
        const float4 e1 = ep[1][row][hh];
        const float4 e2 = ep[2][row][hh];
        const float4 e3 = ep[3][row][hh];
        const float4 bias = *(const float4*)(vb2 + hh * 4);
        float4 oo;
        oo.x = e0.x + e1.x + e2.x + e3.x + bias.x;
        oo.y = e0.y + e1.y + e2.y + e3.y + bias.y;
        oo.z = e0.z + e1.z + e2.z + e3.z + bias.z;
        oo.w = e0.w + e1.w + e2.w + e3.w + bias.w;
        *(float4*)(orow + hh * 4) = oo;        // b128 coalesced store
    }
}

extern "C" void kernel_launch(void* const* d_in, const int* in_sizes, int n_in,
                              void* d_out, int out_size, void* d_ws, size_t ws_size,
                              hipStream_t stream) {
    const float* state   = (const float*)d_in[0];   // [B,T,A,C]
    const float* session = (const float*)d_in[1];   // [B,H]
    const float* query   = (const float*)d_in[4];   // [R]
    const float* pos     = (const float*)d_in[5];   // [C,R]
    const float* kW1     = (const float*)d_in[6];   // [R+H, R]
    const float* kb1     = (const float*)d_in[7];   // [R]
    const float* kW2     = (const float*)d_in[8];   // [R, R]
    const float* vW1     = (const float*)d_in[10];  // [R+H+1, R]
    const float* vb1     = (const float*)d_in[11];  // [R]
    const float* vW2     = (const float*)d_in[12];  // [R, OUT]
    const float* vb2     = (const float*)d_in[13];  // [OUT]

    float* ws  = (float*)d_ws;
    float* out = (float*)d_out;

    prep_kernel<<<137, 256, 0, stream>>>(session, query, pos, kW1, kb1, kW2,
                                         vW1, vb1, ws);
    main_kernel<<<B_ * 32, 512, 0, stream>>>(state, vW1, vW2, vb2, ws, out);
}

// Round 5
// 104.336 us; speedup vs baseline: 1.0442x; 1.0442x over previous
//
#include <hip/hip_runtime.h>
#include <math.h>

// Problem constants
#define B_ 8
#define T_ 256
#define A_ 2
#define C_ 128
#define R_ 128
#define H_ 128
#define OUT_ 256

// Workspace layout (float offsets)
#define WS_PCK 0
#define WS_PCV 16384
#define WS_PSK 32768
#define WS_PSV 33792
#define WS_QK  34816
#define WS_WSM 34944          // softmax weights w[b][c] (1024)
// Taylor-coefficient planes (r-contiguous, [B][C][R]) + S0 [B][R]
#define WS_W1  36864
#define WS_W2  167936
#define WS_W3  299008
#define WS_S0  430080
#define WS_TOTAL 431104  // floats (~1.7 MB)

// gelu via A&S 7.1.27 (|erf err| <= 5e-4), no exp, branchless (scores path).
__device__ __forceinline__ float gelu_fast(float x) {
    const float ax = fabsf(x);
    float q = fmaf(ax, 0.019527f, 0.000343654f);
    q = fmaf(q, ax, 0.1151945f);
    q = fmaf(q, ax, 0.19685217f);
    q = fmaf(q, ax, 1.0f);
    const float r  = __builtin_amdgcn_rcpf(q);
    const float r2 = r * r;
    const float r4 = r2 * r2;
    return fmaf(-0.5f * ax, r4, fmaxf(x, 0.0f));
}

// ---------------------------------------------------------------------------
// Kernel 1: small projection dots into workspace (+ zero S0 accumulator).
// ---------------------------------------------------------------------------
__global__ __launch_bounds__(256) void prep_kernel(
    const float* __restrict__ session,   // [B,H]
    const float* __restrict__ query,     // [R]
    const float* __restrict__ pos,       // [C,R]
    const float* __restrict__ kW1,       // [R+H, R]
    const float* __restrict__ kb1,       // [R]
    const float* __restrict__ kW2,       // [R, R]
    const float* __restrict__ vW1,       // [R+H+1, R]
    const float* __restrict__ vb1,       // [R]
    float* __restrict__ ws)
{
    const int g = blockIdx.x * 256 + threadIdx.x;
    if (g < 16384) {                       // pck[c][r]
        const int c = g >> 7, r = g & 127;
        float acc = 0.0f;
        #pragma unroll 16
        for (int k = 0; k < R_; ++k)
            acc += pos[c * R_ + k] * kW1[k * R_ + r];
        ws[WS_PCK + g] = acc;
    } else if (g < 32768) {                // pcv[c][r]
        const int e = g - 16384;
        const int c = e >> 7, r = e & 127;
        float acc = 0.0f;
        #pragma unroll 16
        for (int k = 0; k < R_; ++k)
            acc += pos[c * R_ + k] * vW1[k * R_ + r];
        ws[WS_PCV + e] = acc;
    } else if (g < 33792) {                // psk[b][r] (+kb1)
        const int e = g - 32768;
        const int b = e >> 7, r = e & 127;
        float acc = kb1[r];
        #pragma unroll 16
        for (int k = 0; k < H_; ++k)
            acc += session[b * H_ + k] * kW1[(R_ + k) * R_ + r];
        ws[WS_PSK + e] = acc;
    } else if (g < 34816) {                // psv[b][r] (+vb1)
        const int e = g - 33792;
        const int b = e >> 7, r = e & 127;
        float acc = vb1[r];
        #pragma unroll 16
        for (int k = 0; k < H_; ++k)
            acc += session[b * H_ + k] * vW1[(R_ + k) * R_ + r];
        ws[WS_PSV + e] = acc;
    } else if (g < 34944) {                // qk[r] = kW2[r,:] . query
        const int r = g - 34816;
        float acc = 0.0f;
        #pragma unroll 16
        for (int j = 0; j < R_; ++j)
            acc += kW2[r * R_ + j] * query[j];
        ws[WS_QK + r] = acc;
    } else if (g < 35968) {                // zero S0[b][r] (atomics target)
        ws[WS_S0 + (g - 34944)] = 0.0f;
    }
}

// ---------------------------------------------------------------------------
// Kernel 2a: scores + softmax, SHUFFLE version. 8 blocks x 1024 threads.
// 2 barriers (vs 17 in the LDS-tree version); reductions via __shfl_xor.
// Writes w[b][c] to WS_WSM.
// ---------------------------------------------------------------------------
__global__ __launch_bounds__(1024) void softmax_kernel(float* __restrict__ ws)
{
    __shared__ float scL[C_];    // raw scores per c
    __shared__ float wL[C_];     // softmax weights

    const int b   = blockIdx.x;
    const int tid = threadIdx.x;
    const int c   = tid >> 3;        // 0..127
    const int rs  = tid & 7;         // r-segment: r in [16*rs, 16*rs+16)

    // segment dot (vectorized float4 loads; 16 floats = 4 float4)
    const float4* __restrict__ pk4 = (const float4*)(ws + WS_PCK + c * R_ + rs * 16);
    const float4* __restrict__ ps4 = (const float4*)(ws + WS_PSK + b * R_ + rs * 16);
    const float4* __restrict__ qk4 = (const float4*)(ws + WS_QK + rs * 16);
    float acc = 0.0f;
    #pragma unroll
    for (int i = 0; i < 4; ++i) {
        const float4 pk = pk4[i];
        const float4 ps = ps4[i];
        const float4 qq = qk4[i];
        acc += gelu_fast(pk.x + ps.x) * qq.x;
        acc += gelu_fast(pk.y + ps.y) * qq.y;
        acc += gelu_fast(pk.z + ps.z) * qq.z;
        acc += gelu_fast(pk.w + ps.w) * qq.w;
    }
    // sum the 8 rs-partials within each 8-lane group
    acc += __shfl_xor(acc, 1);
    acc += __shfl_xor(acc, 2);
    acc += __shfl_xor(acc, 4);
    if (rs == 0) scL[c] = acc * 0.08838834764831845f;   // 1/sqrt(128)
    __syncthreads();

    // wave 0: softmax over 128 c's (2 per lane), shuffle max + sum
    if (tid < 64) {
        const float s0 = scL[tid * 2 + 0];
        const float s1 = scL[tid * 2 + 1];
        float m = fmaxf(s0, s1);
        #pragma unroll
        for (int off = 32; off > 0; off >>= 1) m = fmaxf(m, __shfl_xor(m, off));
        const float e0 = __expf(s0 - m);
        const float e1 = __expf(s1 - m);
        float sum = e0 + e1;
        #pragma unroll
        for (int off = 32; off > 0; off >>= 1) sum += __shfl_xor(sum, off);
        wL[tid * 2 + 0] = e0 / sum;
        wL[tid * 2 + 1] = e1 / sum;
    }
    __syncthreads();
    if (tid < 128) ws[WS_WSM + b * C_ + tid] = wL[tid];
}

// ---------------------------------------------------------------------------
// Kernel 2b: Taylor coefficient planes, WIDE. 512 blocks x 256 threads,
// one (b,c,r) point per thread. Fully coalesced loads/stores.
// S0[b,r]: the block's two c-halves are combined in LDS first -> one
// atomicAdd per (block, r): 65536 atomics, 64-deep per address.
// ---------------------------------------------------------------------------
__global__ __launch_bounds__(256) void coef_kernel(
    const float* __restrict__ vW1,    // [R+H+1, R]; last row = vr
    float* __restrict__ ws)
{
    __shared__ float s0sh[R_];

    const int blk = blockIdx.x;
    const int b   = blk >> 6;              // 0..7
    const int cp  = blk & 63;              // c pair index
    const int tid = threadIdx.x;
    const int c   = cp * 2 + (tid >> 7);   // wave-uniform
    const int r   = tid & 127;

    const float vr  = vW1[(R_ + H_) * R_ + r];
    const float vr2 = vr * vr;
    const float vr3 = vr2 * vr;
    const float cc  = ws[WS_PCV + c * R_ + r] + ws[WS_PSV + b * R_ + r];
    const float wgt = ws[WS_WSM + b * C_ + c];

    // Phi(cc) via A&S 7.1.27 on |cc| (coeffs pre-folded with 1/sqrt2)
    const float ax = fabsf(cc);
    float qq = fmaf(ax, 0.019527f, 0.000343654f);
    qq = fmaf(qq, ax, 0.1151945f);
    qq = fmaf(qq, ax, 0.19685217f);
    qq = fmaf(qq, ax, 1.0f);
    const float qi  = __builtin_amdgcn_rcpf(qq);
    const float qi2 = qi * qi;
    const float h   = 0.5f * qi2 * qi2;          // = Phi(-|cc|)
    const float Phi = (cc >= 0.0f) ? (1.0f - h) : h;
    const float cc2 = cc * cc;
    const float phi = 0.3989422804f * __expf(-0.5f * cc2);
    const float g0 = cc * Phi;
    const float g1 = fmaf(cc, phi, Phi);
    const float g2 = 0.5f * phi * (2.0f - cc2);
    const float g3 = phi * cc * (cc2 - 4.0f) * (1.0f / 6.0f);

    const size_t idx = (size_t)(b * C_ + c) * R_ + r;
    ws[WS_W1 + idx] = wgt * g1 * vr;
    ws[WS_W2 + idx] = wgt * g2 * vr2;
    ws[WS_W3 + idx] = wgt * g3 * vr3;

    const float contrib = wgt * g0;
    if (tid >= 128) s0sh[r] = contrib;
    __syncthreads();
    if (tid < 128) atomicAdd(ws + WS_S0 + b * R_ + r, contrib + s0sh[r]);
}

// ---------------------------------------------------------------------------
// Kernel 3: main. 256 blocks x 512 threads; SIXTEEN (t,a) rows per block.
// (R2 structure -- best measured. R4's full fusion regressed: barriers at
// 1 block/CU are fully exposed; keep coef off the critical path.)
// Phase-2 uses Horner form: s*(W1 + s*(W2 + s*W3)) -- drops s^2/s^3 muls.
// ---------------------------------------------------------------------------
__global__ __launch_bounds__(512) void main_kernel(
    const float* __restrict__ state,  // [B, 512, 128] rows
    const float* __restrict__ vW2,    // [R, OUT]
    const float* __restrict__ vb2,    // [OUT]
    const float* __restrict__ ws,
    float* __restrict__ out)          // [B, 512, OUT]
{
    __shared__ __align__(16) float sv[16 * C_];   // 16 state rows (8 KB)
    __shared__ float4 smem[4][8][R_];             // 64 KB: transpose partials
                                                  // [rquad][seg][r]; reused as
                                                  // ep[4][16][64] in epilogue
    __shared__ float4 p4[4][R_];                  // combined partials, 8 KB
                                                  // quad q = rows 4q..4q+3

    const int blk = blockIdx.x;
    const int b   = blk >> 5;        // / 32
    const int grp = blk & 31;
    const int tid = threadIdx.x;
    const int rh  = tid >> 8;        // row-half: rows rh*8 .. rh*8+7
    const int t2  = tid & 255;
    const int k   = t2 & 31;         // r-quad index: r0 = 4k
    const int seg = t2 >> 5;         // c-segment: c in [16*seg, +16)
    const int r0  = k * 4;

    const float* __restrict__ srow = state + (size_t)(b * 512 + grp * 16) * C_;
    #pragma unroll
    for (int i = 0; i < 4; ++i) sv[tid + 512 * i] = srow[tid + 512 * i];
    __syncthreads();

    const size_t pbase = (size_t)(b * C_) * R_ + r0;
    const float* __restrict__ W1p = ws + WS_W1 + pbase;
    const float* __restrict__ W2p = ws + WS_W2 + pbase;
    const float* __restrict__ W3p = ws + WS_W3 + pbase;

    float4 a[8];
    #pragma unroll
    for (int j = 0; j < 8; ++j) a[j] = make_float4(0.f, 0.f, 0.f, 0.f);

    const int cbeg = seg * 16;
    const int rbase = rh * 8;
    #pragma unroll 2
    for (int i = 0; i < 16; ++i) {
        const int c = cbeg + i;
        const float4 w1 = *(const float4*)(W1p + (size_t)c * R_);  // b128
        const float4 w2 = *(const float4*)(W2p + (size_t)c * R_);  // b128
        const float4 w3 = *(const float4*)(W3p + (size_t)c * R_);  // b128
        #pragma unroll
        for (int j = 0; j < 8; ++j) {
            const float s = sv[(rbase + j) * C_ + c];
            float tx = fmaf(s, w3.x, w2.x); tx = fmaf(s, tx, w1.x); a[j].x = fmaf(s, tx, a[j].x);
            float ty = fmaf(s, w3.y, w2.y); ty = fmaf(s, ty, w1.y); a[j].y = fmaf(s, ty, a[j].y);
            float tz = fmaf(s, w3.z, w2.z); tz = fmaf(s, tz, w1.z); a[j].z = fmaf(s, tz, a[j].z);
            float tw = fmaf(s, w3.w, w2.w); tw = fmaf(s, tw, w1.w); a[j].w = fmaf(s, tw, a[j].w);
        }
    }

    // transpose: smem[rh*2][seg][r] = rows rh*8..+3, smem[rh*2+1] = rows +4..+7
    smem[rh * 2 + 0][seg][r0 + 0] = make_float4(a[0].x, a[1].x, a[2].x, a[3].x);
    smem[rh * 2 + 0][seg][r0 + 1] = make_float4(a[0].y, a[1].y, a[2].y, a[3].y);
    smem[rh * 2 + 0][seg][r0 + 2] = make_float4(a[0].z, a[1].z, a[2].z, a[3].z);
    smem[rh * 2 + 0][seg][r0 + 3] = make_float4(a[0].w, a[1].w, a[2].w, a[3].w);
    smem[rh * 2 + 1][seg][r0 + 0] = make_float4(a[4].x, a[5].x, a[6].x, a[7].x);
    smem[rh * 2 + 1][seg][r0 + 1] = make_float4(a[4].y, a[5].y, a[6].y, a[7].y);
    smem[rh * 2 + 1][seg][r0 + 2] = make_float4(a[4].z, a[5].z, a[6].z, a[7].z);
    smem[rh * 2 + 1][seg][r0 + 3] = make_float4(a[4].w, a[5].w, a[6].w, a[7].w);
    __syncthreads();

    // seg-reduction: all 512 threads busy. qd = row-quad, rr = r.
    {
        const int qd = tid >> 7;         // 0..3
        const int rr = tid & 127;
        float4 v = smem[qd][0][rr];
        #pragma unroll
        for (int sg = 1; sg < 8; ++sg) {
            const float4 t = smem[qd][sg][rr];
            v.x += t.x; v.y += t.y; v.z += t.z; v.w += t.w;
        }
        const float s0v = ws[WS_S0 + b * R_ + rr];  // row-independent term
        v.x += s0v; v.y += s0v; v.z += s0v; v.w += s0v;
        p4[qd][rr] = v;
    }
    __syncthreads();   // smem[] partials dead; reuse as ep[4][16][64]

    // Epilogue: split-K register-tiled GEMM; thread = (erh, kq, hq):
    // 8 rows (its half) x 4 h over 32 r.
    float4 (*ep)[16][64] = (float4 (*)[16][64])smem;   // [kq][row][hq], 64 KB
    const int hq  = tid & 63;
    const int kq  = (tid >> 6) & 3;
    const int erh = tid >> 8;
    const int h0  = hq * 4;

    float4 o[8];
    #pragma unroll
    for (int j = 0; j < 8; ++j) o[j] = make_float4(0.f, 0.f, 0.f, 0.f);
    const int rrb = kq * 32;
    #pragma unroll 4
    for (int i = 0; i < 32; ++i) {
        const int rr = rrb + i;
        const float4 plo = p4[erh * 2 + 0][rr];                    // broadcast
        const float4 phi = p4[erh * 2 + 1][rr];                    // broadcast
        const float4 wv4 = *(const float4*)(vW2 + rr * OUT_ + h0); // coalesced
        o[0].x = fmaf(plo.x, wv4.x, o[0].x); o[0].y = fmaf(plo.x, wv4.y, o[0].y);
        o[0].z = fmaf(plo.x, wv4.z, o[0].z); o[0].w = fmaf(plo.x, wv4.w, o[0].w);
        o[1].x = fmaf(plo.y, wv4.x, o[1].x); o[1].y = fmaf(plo.y, wv4.y, o[1].y);
        o[1].z = fmaf(plo.y, wv4.z, o[1].z); o[1].w = fmaf(plo.y, wv4.w, o[1].w);
        o[2].x = fmaf(plo.z, wv4.x, o[2].x); o[2].y = fmaf(plo.z, wv4.y, o[2].y);
        o[2].z = fmaf(plo.z, wv4.z, o[2].z); o[2].w = fmaf(plo.z, wv4.w, o[2].w);
        o[3].x = fmaf(plo.w, wv4.x, o[3].x); o[3].y = fmaf(plo.w, wv4.y, o[3].y);
        o[3].z = fmaf(plo.w, wv4.z, o[3].z); o[3].w = fmaf(plo.w, wv4.w, o[3].w);
        o[4].x = fmaf(phi.x, wv4.x, o[4].x); o[4].y = fmaf(phi.x, wv4.y, o[4].y);
        o[4].z = fmaf(phi.x, wv4.z, o[4].z); o[4].w = fmaf(phi.x, wv4.w, o[4].w);
        o[5].x = fmaf(phi.y, wv4.x, o[5].x); o[5].y = fmaf(phi.y, wv4.y, o[5].y);
        o[5].z = fmaf(phi.y, wv4.z, o[5].z); o[5].w = fmaf(phi.y, wv4.w, o[5].w);
        o[6].x = fmaf(phi.z, wv4.x, o[6].x); o[6].y = fmaf(phi.z, wv4.y, o[6].y);
        o[6].z = fmaf(phi.z, wv4.z, o[6].z); o[6].w = fmaf(phi.z, wv4.w, o[6].w);
        o[7].x = fmaf(phi.w, wv4.x, o[7].x); o[7].y = fmaf(phi.w, wv4.y, o[7].y);
        o[7].z = fmaf(phi.w, wv4.z, o[7].z); o[7].w = fmaf(phi.w, wv4.w, o[7].w);
    }
    #pragma unroll
    for (int j = 0; j < 8; ++j) ep[kq][erh * 8 + j][hq] = o[j];
    __syncthreads();

    // final combine: thread = (row = tid>>5 (0..15), hq2 = tid&31)
    const int row  = tid >> 5;
    const int hqa  = tid & 31;
    float* __restrict__ orow = out + (size_t)(b * 512 + grp * 16 + row) * OUT_;
    #pragma unroll
    for (int half = 0; half < 2; ++half) {
        const int hh = hqa + half * 32;
        const float4 e0 = ep[0][row][hh];
        const float4 e1 = ep[1][row][hh];
        const float4 e2 = ep[2][row][hh];
        const float4 e3 = ep[3][row][hh];
        const float4 bias = *(const float4*)(vb2 + hh * 4);
        float4 oo;
        oo.x = e0.x + e1.x + e2.x + e3.x + bias.x;
        oo.y = e0.y + e1.y + e2.y + e3.y + bias.y;
        oo.z = e0.z + e1.z + e2.z + e3.z + bias.z;
        oo.w = e0.w + e1.w + e2.w + e3.w + bias.w;
        *(float4*)(orow + hh * 4) = oo;        // b128 coalesced store
    }
}

extern "C" void kernel_launch(void* const* d_in, const int* in_sizes, int n_in,
                              void* d_out, int out_size, void* d_ws, size_t ws_size,
                              hipStream_t stream) {
    const float* state   = (const float*)d_in[0];   // [B,T,A,C]
    const float* session = (const float*)d_in[1];   // [B,H]
    const float* query   = (const float*)d_in[4];   // [R]
    const float* pos     = (const float*)d_in[5];   // [C,R]
    const float* kW1     = (const float*)d_in[6];   // [R+H, R]
    const float* kb1     = (const float*)d_in[7];   // [R]
    const float* kW2     = (const float*)d_in[8];   // [R, R]
    const float* vW1     = (const float*)d_in[10];  // [R+H+1, R]
    const float* vb1     = (const float*)d_in[11];  // [R]
    const float* vW2     = (const float*)d_in[12];  // [R, OUT]
    const float* vb2     = (const float*)d_in[13];  // [OUT]

    float* ws  = (float*)d_ws;
    float* out = (float*)d_out;

    prep_kernel<<<141, 256, 0, stream>>>(session, query, pos, kW1, kb1, kW2,
                                         vW1, vb1, ws);
    softmax_kernel<<<B_, 1024, 0, stream>>>(ws);
    coef_kernel<<<512, 256, 0, stream>>>(vW1, ws);
    main_kernel<<<B_ * 32, 512, 0, stream>>>(state, vW2, vb2, ws, out);
}